// Round 3
// baseline (1575.707 us; speedup 1.0000x reference)
//
#include <hip/hip_runtime.h>
#include <hip/hip_cooperative_groups.h>
#include <cstdint>
#include <cstddef>

namespace cg = cooperative_groups;

// PCFG inside algorithm. B=8, n=28, NT=32, T=64, ST=96.
// Persistent cooperative kernel: grid = B*20 blocks. Block (b, ch) owns a
// 64-float4-column chunk of the packed erule table, staged in LDS once.
// Per width w: all blocks of batch b redundantly finalize width w-1 from
// partial sums (bitwise identical), build exp tables for all spans in LDS,
// build numer for their chunk, contract, write per-chunk partials, grid-sync.
// Quadrants: TT (w==1, 1024 c4, chunks 0..15) | TN (512 c4, ch 0..7)
//            NT (512 c4, ch 8..15) | NN (256 c4, ch 16..19).

#define PS  27
#define PCH 20
#define NMAX 28

__device__ __forceinline__ float dot4acc(float4 m, float4 t, float acc) {
    return fmaf(m.x, t.x, fmaf(m.y, t.y, fmaf(m.z, t.z, fmaf(m.w, t.w, acc))));
}

// ---- mrule[b][a] = max over 96x96 of rule_scores[b][a] ----
__global__ __launch_bounds__(256) void mrule_kernel(const float* __restrict__ rule,
                                                    float* __restrict__ mrule) {
    int a = blockIdx.x, b = blockIdx.y, tid = threadIdx.x;
    const float* base = rule + (size_t)(b * 32 + a) * 9216;
    float v = -3.0e38f;
    for (int i = tid; i < 9216; i += 256) v = fmaxf(v, base[i]);
    for (int off = 32; off > 0; off >>= 1) v = fmaxf(v, __shfl_xor(v, off, 64));
    __shared__ float red[4];
    if ((tid & 63) == 0) red[tid >> 6] = v;
    __syncthreads();
    if (tid == 0)
        mrule[b * 32 + a] = fmaxf(fmaxf(red[0], red[1]), fmaxf(red[2], red[3]));
}

// ---- pack erule = exp(rule - mrule) into quadrant arrays, [c4][a][4] ----
__global__ __launch_bounds__(256) void pack_kernel(const float* __restrict__ rule,
                                                   const float* __restrict__ mrule,
                                                   float* __restrict__ E_TT,
                                                   float* __restrict__ E_TN,
                                                   float* __restrict__ E_NT,
                                                   float* __restrict__ E_NN) {
    int b = blockIdx.y, tid = threadIdx.x;
    int a = tid & 31;
    int cc = blockIdx.x * 8 + (tid >> 5); // 0..2303
    float mr = mrule[b * 32 + a];
    int l, r;
    float* dst;
    if (cc < 1024) {
        int flat = cc * 4;
        l = 32 + (flat >> 6); r = 32 + (flat & 63);
        dst = E_TT + ((size_t)(b * 1024 + cc) * 32 + a) * 4;
    } else if (cc < 1536) {
        int flat = (cc - 1024) * 4;
        l = 32 + (flat >> 5); r = flat & 31;
        dst = E_TN + ((size_t)(b * 512 + (cc - 1024)) * 32 + a) * 4;
    } else if (cc < 2048) {
        int flat = (cc - 1536) * 4;
        l = flat >> 6; r = 32 + (flat & 63);
        dst = E_NT + ((size_t)(b * 512 + (cc - 1536)) * 32 + a) * 4;
    } else {
        int flat = (cc - 2048) * 4;
        l = flat >> 5; r = flat & 31;
        dst = E_NN + ((size_t)(b * 256 + (cc - 2048)) * 32 + a) * 4;
    }
    const float4 v = *(const float4*)(rule + (((size_t)(b * 32 + a) * 96 + l) * 96 + r));
    float4 o;
    o.x = expf(v.x - mr); o.y = expf(v.y - mr);
    o.z = expf(v.z - mr); o.w = expf(v.w - mr);
    *(float4*)dst = o;
}

// ---- persistent inside kernel ----
__global__ __launch_bounds__(256, 1) void inside_kernel(
    const float* __restrict__ unary,   // B,n,64
    const float* __restrict__ mrule,   // B,32
    const float* __restrict__ root,    // B,32
    float* __restrict__ beta_n,        // B,n,n,32 (width rows >=1)
    const float* __restrict__ E_TT, const float* __restrict__ E_TN,
    const float* __restrict__ E_NT, const float* __restrict__ E_NN,
    float* __restrict__ partA, float* __restrict__ partB,
    float* __restrict__ out, int n) {
    const int blk = blockIdx.x;
    const int b = blk / 20, ch = blk % 20;
    const int tid = threadIdx.x;
    const int g = tid >> 5, a = tid & 31;

    __shared__ __align__(16) float4 eLds[2048];          // 32KB E chunk
    __shared__ __align__(16) float numerLds[PS * 256];   // 27.6KB
    __shared__ float elN[5824], erN[5824];               // (w-1)*S*32 max
    __shared__ float el0T[PS * 64], erT[PS * 64];
    __shared__ float unaryLds[NMAX * 64];
    __shared__ float bmaxAll[NMAX][NMAX];                // [width_row][pos]
    __shared__ float Mspan[NMAX];
    __shared__ float mruleLds[32];
    __shared__ float betaTmp[PS * 32];

    // preload unary + mrule
    for (int i = tid; i < n * 64; i += 256) unaryLds[i] = unary[(size_t)b * n * 64 + i];
    if (tid < 32) mruleLds[tid] = mrule[b * 32 + tid];

    // stage E chunk: ch<16 -> TT (for w==1); ch>=16 -> NN (their w>=3 chunk)
    {
        const float4* src = (ch < 16)
            ? (const float4*)E_TT + ((size_t)b * 1024 + ch * 64) * 32
            : (const float4*)E_NN + ((size_t)b * 256 + (ch - 16) * 64) * 32;
        #pragma unroll
        for (int i = 0; i < 8; ++i) eLds[tid + i * 256] = src[tid + i * 256];
    }

    cg::grid_group grid = cg::this_grid();

    for (int w = 1; w < n; ++w) {
        const int S = n - w;

        // ---- phase A: prologue ----
        if (w == 1) {
            for (int s = tid; s < n; s += 256) {
                float m = -3.0e38f;
                for (int t = 0; t < 64; ++t) m = fmaxf(m, unaryLds[s * 64 + t]);
                bmaxAll[0][s] = m;
            }
        } else {
            const int wp = w - 1, Sp = S + 1;
            const int CHp = (wp <= 2) ? 16 : 20;
            const float* pin = ((w & 1) ? partA : partB) + (size_t)b * (PS * 32 * PCH);
            for (int e = tid; e < Sp * 32; e += 256) {
                const float4* p4 = (const float4*)(pin + e * PCH);
                float4 q0 = p4[0], q1 = p4[1], q2 = p4[2], q3 = p4[3];
                float t = ((q0.x + q0.y) + (q0.z + q0.w)) + ((q1.x + q1.y) + (q1.z + q1.w))
                        + ((q2.x + q2.y) + (q2.z + q2.w)) + ((q3.x + q3.y) + (q3.z + q3.w));
                if (CHp == 20) { float4 q4 = p4[4]; t += ((q4.x + q4.y) + (q4.z + q4.w)); }
                int s = e >> 5, aa = e & 31;
                float score = logf(t) + Mspan[s] + mruleLds[aa];
                betaTmp[e] = score;
                beta_n[(((size_t)b * n + wp) * n + s) * 32 + aa] = score;
            }
            // restage E for TT->TN/NT switch
            if (w == 2 && ch < 16) {
                const float4* src = (ch < 8)
                    ? (const float4*)E_TN + ((size_t)b * 512 + ch * 64) * 32
                    : (const float4*)E_NT + ((size_t)b * 512 + (ch - 8) * 64) * 32;
                #pragma unroll
                for (int i = 0; i < 8; ++i) eLds[tid + i * 256] = src[tid + i * 256];
            }
        }
        __syncthreads();
        if (w >= 2) {
            const int wp = w - 1, Sp = S + 1;
            for (int s = tid; s < Sp; s += 256) {
                float m = -3.0e38f;
                for (int aa = 0; aa < 32; ++aa) m = fmaxf(m, betaTmp[s * 32 + aa]);
                bmaxAll[wp][s] = m;
            }
            __syncthreads();
        }

        // ---- phase B: Mspan ----
        for (int s = tid; s < S; s += 256) {
            float M = -3.0e38f;
            for (int k = 0; k < w; ++k)
                M = fmaxf(M, bmaxAll[k][s] + bmaxAll[w - 1 - k][s + k + 1]);
            Mspan[s] = M;
        }
        __syncthreads();

        // ---- phase C: exp tables ----
        for (int i = tid; i < S * 64; i += 256) {
            int s = i >> 6, t = i & 63;
            el0T[i] = expf(unaryLds[s * 64 + t] - bmaxAll[0][s]);
            erT[i]  = expf(unaryLds[(s + w) * 64 + t] + bmaxAll[w - 1][s] - Mspan[s]);
        }
        for (int k1 = 0; k1 < w - 1; ++k1) {
            const int kl = k1 + 1, kr = k1;
            const float* bl = beta_n + (((size_t)b * n + kl) * n) * 32;
            const float* br = beta_n + (((size_t)b * n + (w - 1 - kr)) * n) * 32;
            for (int i = tid; i < S * 32; i += 256) {
                int s = i >> 5, sym = i & 31;
                elN[k1 * (S * 32) + i] = expf(bl[s * 32 + sym] - bmaxAll[kl][s]);
                erN[k1 * (S * 32) + i] =
                    expf(br[(s + kr + 1) * 32 + sym] + bmaxAll[kr][s] - Mspan[s]);
            }
        }
        __syncthreads();

        // ---- phase D: numer for this chunk ----
        const bool active = (w == 1) ? (ch < 16) : !(w == 2 && ch >= 16);
        const int quad = (w == 1) ? 0 : (ch < 8 ? 1 : (ch < 16 ? 2 : 3));
        const int base4 = (w == 1) ? ch * 64
                        : (ch < 8 ? ch * 64 : (ch < 16 ? (ch - 8) * 64 : (ch - 16) * 64));
        if (active) {
            for (int i = tid; i < S * 256; i += 256) {
                int s = i >> 8, j = i & 255;
                int p = base4 * 4 + j;
                float v;
                if (quad == 0)      v = el0T[s * 64 + (p >> 6)] * erT[s * 64 + (p & 63)];
                else if (quad == 1) v = el0T[s * 64 + (p >> 5)] * erN[s * 32 + (p & 31)];
                else if (quad == 2) v = elN[(w - 2) * (S * 32) + s * 32 + (p >> 6)] *
                                        erT[s * 64 + (p & 63)];
                else {
                    int l = p >> 5, r = p & 31;
                    float acc = 0.f;
                    for (int k = 1; k <= w - 2; ++k)
                        acc = fmaf(elN[(k - 1) * (S * 32) + s * 32 + l],
                                   erN[k * (S * 32) + s * 32 + r], acc);
                    v = acc;
                }
                numerLds[i] = v;
            }
        }
        __syncthreads();

        // ---- phase E: contraction, 4 spans per thread ----
        if (active) {
            float* pout = ((w & 1) ? partB : partA) + (size_t)b * (PS * 32 * PCH);
            const float4* n4 = (const float4*)numerLds;
            const int s1 = g + 8, s2 = g + 16, s3 = g + 24;
            float acc0 = 0.f, acc1 = 0.f, acc2 = 0.f, acc3 = 0.f;
            #pragma unroll 8
            for (int c = 0; c < 64; ++c) {
                float4 e4 = eLds[c * 32 + a];
                acc0 = dot4acc(n4[g * 64 + c], e4, acc0);
                if (s1 < S) acc1 = dot4acc(n4[s1 * 64 + c], e4, acc1);
                if (s2 < S) acc2 = dot4acc(n4[s2 * 64 + c], e4, acc2);
                if (s3 < S) acc3 = dot4acc(n4[s3 * 64 + c], e4, acc3);
            }
            if (g < S)  pout[(g  * 32 + a) * PCH + ch] = acc0;
            if (s1 < S) pout[(s1 * 32 + a) * PCH + ch] = acc1;
            if (s2 < S) pout[(s2 * 32 + a) * PCH + ch] = acc2;
            if (s3 < S) pout[(s3 * 32 + a) * PCH + ch] = acc3;
        }
        __threadfence();
        grid.sync();
    }

    // ---- epilogue: width n-1 finalize + root + logsumexp ----
    if (ch == 0 && tid < 32) {
        const float* pin = (((n - 1) & 1) ? partB : partA) + (size_t)b * (PS * 32 * PCH);
        const float4* p4 = (const float4*)(pin + tid * PCH);
        float4 q0 = p4[0], q1 = p4[1], q2 = p4[2], q3 = p4[3], q4 = p4[4];
        float t = ((q0.x + q0.y) + (q0.z + q0.w)) + ((q1.x + q1.y) + (q1.z + q1.w))
                + ((q2.x + q2.y) + (q2.z + q2.w)) + ((q3.x + q3.y) + (q3.z + q3.w))
                + ((q4.x + q4.y) + (q4.z + q4.w));
        float v = logf(t) + Mspan[0] + mruleLds[tid] + root[b * 32 + tid];
        float m = v;
        for (int off = 16; off > 0; off >>= 1) m = fmaxf(m, __shfl_xor(m, off, 32));
        float e = expf(v - m);
        for (int off = 16; off > 0; off >>= 1) e += __shfl_xor(e, off, 32);
        if (tid == 0) out[b] = m + logf(e);
    }
}

extern "C" void kernel_launch(void* const* d_in, const int* in_sizes, int n_in,
                              void* d_out, int out_size, void* d_ws, size_t ws_size,
                              hipStream_t stream) {
    const float* unary = (const float*)d_in[0]; // B,n,64
    const float* rule  = (const float*)d_in[1]; // B,32,96,96
    const float* root  = (const float*)d_in[2]; // B,32
    float* out = (float*)d_out;

    const int B = in_sizes[2] / 32;
    int n = in_sizes[0] / (B * 64);

    float* ws = (float*)d_ws;
    float* mrule  = ws;                                  // B*32
    float* beta_n = mrule + (size_t)B * 32;              // B*n*n*32
    float* E_TT   = beta_n + (size_t)B * n * n * 32;     // B*1024*32*4
    float* E_TN   = E_TT + (size_t)B * 131072;           // B*512*32*4
    float* E_NT   = E_TN + (size_t)B * 65536;            // B*512*32*4
    float* E_NN   = E_NT + (size_t)B * 65536;            // B*256*32*4
    float* partA  = E_NN + (size_t)B * 32768;            // B*PS*32*PCH
    float* partB  = partA + (size_t)B * PS * 32 * PCH;

    mrule_kernel<<<dim3(32, B), 256, 0, stream>>>(rule, mrule);
    pack_kernel<<<dim3(288, B), 256, 0, stream>>>(rule, mrule, E_TT, E_TN, E_NT, E_NN);

    const float* unary_p = unary;
    const float* mrule_p = mrule;
    const float* root_p = root;
    void* args[] = {
        (void*)&unary_p, (void*)&mrule_p, (void*)&root_p, (void*)&beta_n,
        (void*)&E_TT, (void*)&E_TN, (void*)&E_NT, (void*)&E_NN,
        (void*)&partA, (void*)&partB, (void*)&out, (void*)&n
    };
    hipLaunchCooperativeKernel((void*)inside_kernel, dim3(B * 20), dim3(256),
                               args, 0, stream);
}